// Round 3
// baseline (380.219 us; speedup 1.0000x reference)
//
#include <hip/hip_runtime.h>
#include <hip/hip_bf16.h>
#include <stdint.h>
#include <string.h>

#define NN 40000
#define NE 640000
#define D  128
#define NL 4
#define EPSV 1e-6f

typedef __attribute__((ext_vector_type(8))) short          s16x8;
typedef __attribute__((ext_vector_type(8))) unsigned short u16x8;
typedef __attribute__((ext_vector_type(4))) float          f32x4;

static __device__ __forceinline__ unsigned short f2b_bits(float f) {
  uint32_t u = __float_as_uint(f);
  uint32_t r = (u + 0x7fffu + ((u >> 16) & 1u)) >> 16;   // RNE
  return (unsigned short)r;
}
static __device__ __forceinline__ float blo(uint32_t p) { return __uint_as_float(p << 16); }
static __device__ __forceinline__ float bhi(uint32_t p) { return __uint_as_float(p & 0xffff0000u); }

// ---------------- weight prep: fp32 -> bf16 bits ----------------
__global__ void k_prep(const float* __restrict__ Wc, const float* __restrict__ Wh,
                       unsigned short* __restrict__ wcb, unsigned short* __restrict__ whb) {
  int i = blockIdx.x * 256 + threadIdx.x;
  if (i < NL * D * D) {
    wcb[i] = f2b_bits(Wc[i]);
    whb[i] = f2b_bits(Wh[i]);
  }
}

// ---------------- CSR build (scan-free) ----------------
__global__ void k_count(const int* __restrict__ e, int* __restrict__ deg) {
  int i = blockIdx.x * 256 + threadIdx.x;
  if (i < NE) atomicAdd(&deg[e[2 * i + 1]], 1);
}

__global__ void k_alloc(const int* __restrict__ deg, int* __restrict__ total,
                        int* __restrict__ rs) {
  int i = blockIdx.x * 256 + threadIdx.x;
  if (i < NN) rs[i] = atomicAdd(total, deg[i]);
}

__global__ void k_fill(const int* __restrict__ e, const int* __restrict__ rs,
                       int* __restrict__ cursor, int* __restrict__ csr) {
  int i = blockIdx.x * 256 + threadIdx.x;
  if (i < NE) {
    int s = e[2 * i + 0];
    int d = e[2 * i + 1];
    int p = atomicAdd(&cursor[d], 1);
    csr[rs[d] + p] = s;
  }
}

// ---------------- layer-0 edge GEMM: t = relu(x @ Wc^T + bc) -> bf16 ----------------
__global__ __launch_bounds__(256) void k_gemm0(
    const float* __restrict__ hin,
    const unsigned short* __restrict__ Wb,
    const float* __restrict__ bias,
    unsigned short* __restrict__ tout) {
  __shared__ float lds[4][16][D];
  int wave = threadIdx.x >> 6, lane = threadIdx.x & 63;
  int rowbase = (blockIdx.x * 4 + wave) * 16;
  int c15 = lane & 15, grp = lane >> 4;

  s16x8 a[4];
  {
    const float* hp = hin + (size_t)(rowbase + c15) * D;
#pragma unroll
    for (int ks = 0; ks < 4; ++ks) {
      int k0 = ks * 32 + grp * 8;
      f32x4 x0 = *(const f32x4*)(hp + k0);
      f32x4 x1 = *(const f32x4*)(hp + k0 + 4);
      u16x8 av;
      av[0] = f2b_bits(x0[0]); av[1] = f2b_bits(x0[1]);
      av[2] = f2b_bits(x0[2]); av[3] = f2b_bits(x0[3]);
      av[4] = f2b_bits(x1[0]); av[5] = f2b_bits(x1[1]);
      av[6] = f2b_bits(x1[2]); av[7] = f2b_bits(x1[3]);
      a[ks] = __builtin_bit_cast(s16x8, av);
    }
  }

  f32x4 acc[8];
#pragma unroll
  for (int ct = 0; ct < 8; ++ct) { f32x4 z = {0.f, 0.f, 0.f, 0.f}; acc[ct] = z; }
#pragma unroll
  for (int ct = 0; ct < 8; ++ct) {
    const unsigned short* wp = Wb + (size_t)(ct * 16 + c15) * D;
#pragma unroll
    for (int ks = 0; ks < 4; ++ks) {
      s16x8 b = *(const s16x8*)(wp + ks * 32 + grp * 8);
      acc[ct] = __builtin_amdgcn_mfma_f32_16x16x32_bf16(a[ks], b, acc[ct], 0, 0, 0);
    }
  }
#pragma unroll
  for (int ct = 0; ct < 8; ++ct) {
    int col = ct * 16 + c15;
    float bv = bias[col];
#pragma unroll
    for (int r = 0; r < 4; ++r)
      lds[wave][grp * 4 + r][col] = fmaxf(acc[ct][r] + bv, 0.f);
  }
  __syncthreads();
#pragma unroll
  for (int it = 0; it < 4; ++it) {
    int idx = it * 512 + lane * 8;
    int r = idx >> 7, c = idx & 127;
    const float* lp = &lds[wave][r][c];
    f32x4 v0 = *(const f32x4*)lp;
    f32x4 v1 = *(const f32x4*)(lp + 4);
    u16x8 ov;
    ov[0] = f2b_bits(v0[0]); ov[1] = f2b_bits(v0[1]);
    ov[2] = f2b_bits(v0[2]); ov[3] = f2b_bits(v0[3]);
    ov[4] = f2b_bits(v1[0]); ov[5] = f2b_bits(v1[1]);
    ov[6] = f2b_bits(v1[2]); ov[7] = f2b_bits(v1[3]);
    *(u16x8*)(tout + (size_t)(rowbase + r) * D + c) = ov;
  }
}

// ---------------- full layer, barrier-free (each wave owns 16 nodes) ----------------
// phase1: gather-max over t rows + residual + rmsnorm -> h1 in LDS
// phase2: h2 = rmsnorm(h1 + relu(h1@Wh^T+bh)) -> hout; opt t' = relu(h2@Wc'^T+bc')
template <int WRITE_T>
__global__ __launch_bounds__(256) void k_layer(
    const float* __restrict__ hin,
    const uint32_t* __restrict__ tp,       // bf16x2 rows [NN][64]
    const int* __restrict__ rs, const int* __restrict__ deg, const int* __restrict__ csr,
    const float* __restrict__ gcv, const float* __restrict__ bgcv,
    const unsigned short* __restrict__ Whb, const float* __restrict__ bhv,
    const float* __restrict__ ghv, const float* __restrict__ bghv,
    const unsigned short* __restrict__ Wcb, const float* __restrict__ bcv,
    float* __restrict__ hout, unsigned short* __restrict__ tout) {
  __shared__ float u[4][16][132];
  int wave = threadIdx.x >> 6, lane = threadIdx.x & 63;
  int q = lane & 15, g = lane >> 4;
  int rowbase = (blockIdx.x * 4 + wave) * 16;

  // ---- phase 1 ----
  int dim = q * 8 + g * 2;                       // lane's owned dim pair
  float2 gc2  = *(const float2*)(gcv + dim);
  float2 bgc2 = *(const float2*)(bgcv + dim);
  const uint4* tq = (const uint4*)tp;            // 16B granules; row = 16 granules

  for (int nl = 0; nl < 16; ++nl) {
    int n = rowbase + nl;
    int r0 = rs[n], r1 = r0 + deg[n];
    float m8[8];
#pragma unroll
    for (int j = 0; j < 8; ++j) m8[j] = 0.f;
    for (int i = r0; i < r1; i += 8) {
      int e0 = i + g;     if (e0 > r1 - 1) e0 = r1 - 1;   // duplicate-last: max-safe
      int e1 = i + 4 + g; if (e1 > r1 - 1) e1 = r1 - 1;
      int s0 = csr[e0];
      int s1 = csr[e1];
      uint4 p0 = tq[(size_t)s0 * 16 + q];
      uint4 p1 = tq[(size_t)s1 * 16 + q];
      m8[0] = fmaxf(m8[0], blo(p0.x)); m8[1] = fmaxf(m8[1], bhi(p0.x));
      m8[2] = fmaxf(m8[2], blo(p0.y)); m8[3] = fmaxf(m8[3], bhi(p0.y));
      m8[4] = fmaxf(m8[4], blo(p0.z)); m8[5] = fmaxf(m8[5], bhi(p0.z));
      m8[6] = fmaxf(m8[6], blo(p0.w)); m8[7] = fmaxf(m8[7], bhi(p0.w));
      m8[0] = fmaxf(m8[0], blo(p1.x)); m8[1] = fmaxf(m8[1], bhi(p1.x));
      m8[2] = fmaxf(m8[2], blo(p1.y)); m8[3] = fmaxf(m8[3], bhi(p1.y));
      m8[4] = fmaxf(m8[4], blo(p1.z)); m8[5] = fmaxf(m8[5], bhi(p1.z));
      m8[6] = fmaxf(m8[6], blo(p1.w)); m8[7] = fmaxf(m8[7], bhi(p1.w));
    }
    // combine the 4 edge-groups (lanes q,q+16,q+32,q+48 hold partials per dim)
#pragma unroll
    for (int j = 0; j < 8; ++j) {
      m8[j] = fmaxf(m8[j], __shfl_xor(m8[j], 16));
      m8[j] = fmaxf(m8[j], __shfl_xor(m8[j], 32));
    }
    // pick this lane's dim pair (static indices only; cndmask select)
    float a0 = (g & 2) ? ((g & 1) ? m8[6] : m8[4]) : ((g & 1) ? m8[2] : m8[0]);
    float a1 = (g & 2) ? ((g & 1) ? m8[7] : m8[5]) : ((g & 1) ? m8[3] : m8[1]);
    float2 hv = *(const float2*)(hin + (size_t)n * D + dim);
    float u0 = hv.x + a0, u1 = hv.y + a1;
    float ss = u0 * u0 + u1 * u1;
#pragma unroll
    for (int off = 32; off; off >>= 1) ss += __shfl_xor(ss, off);
    float rf = rsqrtf(ss * (1.f / D) + EPSV);
    u[wave][nl][dim]     = u0 * rf * gc2.x + bgc2.x;
    u[wave][nl][dim + 1] = u1 * rf * gc2.y + bgc2.y;
  }

  // ---- phase 2: MLP GEMM from LDS h1 ----
  s16x8 a[4];
#pragma unroll
  for (int ks = 0; ks < 4; ++ks) {
    int k0 = ks * 32 + g * 8;
    f32x4 x0 = *(const f32x4*)&u[wave][q][k0];
    f32x4 x1 = *(const f32x4*)&u[wave][q][k0 + 4];
    u16x8 av;
    av[0] = f2b_bits(x0[0]); av[1] = f2b_bits(x0[1]);
    av[2] = f2b_bits(x0[2]); av[3] = f2b_bits(x0[3]);
    av[4] = f2b_bits(x1[0]); av[5] = f2b_bits(x1[1]);
    av[6] = f2b_bits(x1[2]); av[7] = f2b_bits(x1[3]);
    a[ks] = __builtin_bit_cast(s16x8, av);
  }
  f32x4 acc[8];
#pragma unroll
  for (int ct = 0; ct < 8; ++ct) { f32x4 z = {0.f, 0.f, 0.f, 0.f}; acc[ct] = z; }
#pragma unroll
  for (int ct = 0; ct < 8; ++ct) {
    const unsigned short* wp = Whb + (size_t)(ct * 16 + q) * D;
#pragma unroll
    for (int ks = 0; ks < 4; ++ks) {
      s16x8 b = *(const s16x8*)(wp + ks * 32 + g * 8);
      acc[ct] = __builtin_amdgcn_mfma_f32_16x16x32_bf16(a[ks], b, acc[ct], 0, 0, 0);
    }
  }
  // residual in LDS: u = h1 + relu(acc + bias)
#pragma unroll
  for (int ct = 0; ct < 8; ++ct) {
    int col = ct * 16 + q;
    float bv = bhv[col];
#pragma unroll
    for (int r = 0; r < 4; ++r)
      u[wave][g * 4 + r][col] += fmaxf(acc[ct][r] + bv, 0.f);
  }
  // rmsnorm rows; write h2 to global + back to LDS
  {
    int d0 = lane * 2;
    float2 gh2  = *(const float2*)(ghv + d0);
    float2 bgh2 = *(const float2*)(bghv + d0);
    for (int r = 0; r < 16; ++r) {
      float u0 = u[wave][r][d0], u1 = u[wave][r][d0 + 1];
      float ss = u0 * u0 + u1 * u1;
#pragma unroll
      for (int off = 32; off; off >>= 1) ss += __shfl_xor(ss, off);
      float rf = rsqrtf(ss * (1.f / D) + EPSV);
      float o0 = u0 * rf * gh2.x + bgh2.x;
      float o1 = u1 * rf * gh2.y + bgh2.y;
      u[wave][r][d0]     = o0;
      u[wave][r][d0 + 1] = o1;
      float2 o; o.x = o0; o.y = o1;
      *(float2*)(hout + (size_t)(rowbase + r) * D + d0) = o;
    }
  }

  if (WRITE_T) {
    // next-layer edge GEMM straight from LDS h2
    s16x8 a2[4];
#pragma unroll
    for (int ks = 0; ks < 4; ++ks) {
      int k0 = ks * 32 + g * 8;
      f32x4 x0 = *(const f32x4*)&u[wave][q][k0];
      f32x4 x1 = *(const f32x4*)&u[wave][q][k0 + 4];
      u16x8 av;
      av[0] = f2b_bits(x0[0]); av[1] = f2b_bits(x0[1]);
      av[2] = f2b_bits(x0[2]); av[3] = f2b_bits(x0[3]);
      av[4] = f2b_bits(x1[0]); av[5] = f2b_bits(x1[1]);
      av[6] = f2b_bits(x1[2]); av[7] = f2b_bits(x1[3]);
      a2[ks] = __builtin_bit_cast(s16x8, av);
    }
    f32x4 acc2[8];
#pragma unroll
    for (int ct = 0; ct < 8; ++ct) { f32x4 z = {0.f, 0.f, 0.f, 0.f}; acc2[ct] = z; }
#pragma unroll
    for (int ct = 0; ct < 8; ++ct) {
      const unsigned short* wp = Wcb + (size_t)(ct * 16 + q) * D;
#pragma unroll
      for (int ks = 0; ks < 4; ++ks) {
        s16x8 b = *(const s16x8*)(wp + ks * 32 + g * 8);
        acc2[ct] = __builtin_amdgcn_mfma_f32_16x16x32_bf16(a2[ks], b, acc2[ct], 0, 0, 0);
      }
    }
#pragma unroll
    for (int ct = 0; ct < 8; ++ct) {
      int col = ct * 16 + q;
      float bv = bcv[col];
#pragma unroll
      for (int r = 0; r < 4; ++r)
        u[wave][g * 4 + r][col] = fmaxf(acc2[ct][r] + bv, 0.f);
    }
    // coalesced bf16 store of t'
#pragma unroll
    for (int it = 0; it < 4; ++it) {
      int idx = it * 512 + lane * 8;
      int r = idx >> 7, c = idx & 127;
      f32x4 v0 = *(const f32x4*)&u[wave][r][c];
      f32x4 v1 = *(const f32x4*)&u[wave][r][c + 4];
      u16x8 ov;
      ov[0] = f2b_bits(v0[0]); ov[1] = f2b_bits(v0[1]);
      ov[2] = f2b_bits(v0[2]); ov[3] = f2b_bits(v0[3]);
      ov[4] = f2b_bits(v1[0]); ov[5] = f2b_bits(v1[1]);
      ov[6] = f2b_bits(v1[2]); ov[7] = f2b_bits(v1[3]);
      *(u16x8*)(tout + (size_t)(rowbase + r) * D + c) = ov;
    }
  }
}

// ---------------- launch ----------------
extern "C" void kernel_launch(void* const* d_in, const int* in_sizes, int n_in,
                              void* d_out, int out_size, void* d_ws, size_t ws_size,
                              hipStream_t stream) {
  (void)in_sizes; (void)n_in; (void)out_size; (void)ws_size;
  const float* x   = (const float*)d_in[0];
  const int*   e   = (const int*)d_in[1];
  const float* Wc  = (const float*)d_in[2];
  const float* bc  = (const float*)d_in[3];
  const float* gc  = (const float*)d_in[4];
  const float* bgc = (const float*)d_in[5];
  const float* Wh  = (const float*)d_in[6];
  const float* bh  = (const float*)d_in[7];
  const float* gh  = (const float*)d_in[8];
  const float* bgh = (const float*)d_in[9];
  float* out = (float*)d_out;

  char* base = (char*)d_ws;
  unsigned short* t0  = (unsigned short*)(base + 0);          // 10,240,000
  unsigned short* t1  = (unsigned short*)(base + 10240000);   // 10,240,000
  float*          hA  = (float*)(base + 20480000);            // 20,480,000
  unsigned short* wcb = (unsigned short*)(base + 40960000);   //    131,072
  unsigned short* whb = (unsigned short*)(base + 41091072);   //    131,072
  int*            deg = (int*)(base + 41222144);              //    160,000
  int*            cur = (int*)(base + 41382144);              //    160,000
  int*            tot = (int*)(base + 41542144);              //         64
  int*            rs  = (int*)(base + 41542208);              //    160,000
  int*            csr = (int*)(base + 41702208);              //  2,560,000

  k_prep<<<512, 256, 0, stream>>>(Wc, Wh, wcb, whb);
  hipMemsetAsync(deg, 0, 2 * 160000 + 64, stream);   // deg | cur | tot
  k_count<<<2500, 256, 0, stream>>>(e, deg);
  k_alloc<<<157, 256, 0, stream>>>(deg, tot, rs);
  k_fill<<<2500, 256, 0, stream>>>(e, rs, cur, csr);

  // layer-0 t on x
  k_gemm0<<<625, 256, 0, stream>>>(x, wcb, bc, t0);

  unsigned short* tbuf[2] = {t0, t1};
  for (int l = 0; l < NL; ++l) {
    const float* hin = (l == 0) ? x : hA;
    const uint32_t* tin = (const uint32_t*)tbuf[l & 1];
    if (l < NL - 1) {
      k_layer<1><<<625, 256, 0, stream>>>(
          hin, tin, rs, deg, csr,
          gc + l * D, bgc + l * D,
          whb + (size_t)l * D * D, bh + l * D, gh + l * D, bgh + l * D,
          wcb + (size_t)(l + 1) * D * D, bc + (l + 1) * D,
          hA, tbuf[(l + 1) & 1]);
    } else {
      k_layer<0><<<625, 256, 0, stream>>>(
          hin, tin, rs, deg, csr,
          gc + l * D, bgc + l * D,
          whb + (size_t)l * D * D, bh + l * D, gh + l * D, bgh + l * D,
          nullptr, nullptr,
          out, nullptr);
    }
  }
}

// Round 4
// 332.027 us; speedup vs baseline: 1.1451x; 1.1451x over previous
//
#include <hip/hip_runtime.h>
#include <hip/hip_bf16.h>
#include <stdint.h>
#include <string.h>

#define NN 40000
#define NE 640000
#define D  128
#define NL 4
#define EPSV 1e-6f

typedef __attribute__((ext_vector_type(8))) short          s16x8;
typedef __attribute__((ext_vector_type(8))) unsigned short u16x8;
typedef __attribute__((ext_vector_type(4))) float          f32x4;

static __device__ __forceinline__ unsigned short f2b_bits(float f) {
  uint32_t u = __float_as_uint(f);
  uint32_t r = (u + 0x7fffu + ((u >> 16) & 1u)) >> 16;   // RNE
  return (unsigned short)r;
}
static __device__ __forceinline__ float blo(uint32_t p) { return __uint_as_float(p << 16); }
static __device__ __forceinline__ float bhi(uint32_t p) { return __uint_as_float(p & 0xffff0000u); }

// ---------------- weight prep: fp32 -> bf16 bits ----------------
__global__ void k_prep(const float* __restrict__ Wc, const float* __restrict__ Wh,
                       unsigned short* __restrict__ wcb, unsigned short* __restrict__ whb) {
  int i = blockIdx.x * 256 + threadIdx.x;
  if (i < NL * D * D) {
    wcb[i] = f2b_bits(Wc[i]);
    whb[i] = f2b_bits(Wh[i]);
  }
}

// ---------------- CSR build (scan-free) ----------------
__global__ void k_count(const int* __restrict__ e, int* __restrict__ deg) {
  int i = blockIdx.x * 256 + threadIdx.x;
  if (i < NE) atomicAdd(&deg[e[2 * i + 1]], 1);
}

__global__ void k_alloc(const int* __restrict__ deg, int* __restrict__ total,
                        int* __restrict__ rs) {
  int i = blockIdx.x * 256 + threadIdx.x;
  if (i < NN) rs[i] = atomicAdd(total, deg[i]);
}

__global__ void k_fill(const int* __restrict__ e, const int* __restrict__ rs,
                       int* __restrict__ cursor, int* __restrict__ csr) {
  int i = blockIdx.x * 256 + threadIdx.x;
  if (i < NE) {
    int s = e[2 * i + 0];
    int d = e[2 * i + 1];
    int p = atomicAdd(&cursor[d], 1);
    csr[rs[d] + p] = s;
  }
}

// ---------------- layer-0 edge GEMM: t = relu(x @ Wc^T + bc) -> bf16 ----------------
__global__ __launch_bounds__(256) void k_gemm0(
    const float* __restrict__ hin,
    const unsigned short* __restrict__ Wb,
    const float* __restrict__ bias,
    unsigned short* __restrict__ tout) {
  __shared__ float lds[4][16][D];
  int wave = threadIdx.x >> 6, lane = threadIdx.x & 63;
  int rowbase = (blockIdx.x * 4 + wave) * 16;
  int c15 = lane & 15, grp = lane >> 4;

  s16x8 a[4];
  {
    const float* hp = hin + (size_t)(rowbase + c15) * D;
#pragma unroll
    for (int ks = 0; ks < 4; ++ks) {
      int k0 = ks * 32 + grp * 8;
      f32x4 x0 = *(const f32x4*)(hp + k0);
      f32x4 x1 = *(const f32x4*)(hp + k0 + 4);
      u16x8 av;
      av[0] = f2b_bits(x0[0]); av[1] = f2b_bits(x0[1]);
      av[2] = f2b_bits(x0[2]); av[3] = f2b_bits(x0[3]);
      av[4] = f2b_bits(x1[0]); av[5] = f2b_bits(x1[1]);
      av[6] = f2b_bits(x1[2]); av[7] = f2b_bits(x1[3]);
      a[ks] = __builtin_bit_cast(s16x8, av);
    }
  }

  f32x4 acc[8];
#pragma unroll
  for (int ct = 0; ct < 8; ++ct) { f32x4 z = {0.f, 0.f, 0.f, 0.f}; acc[ct] = z; }
#pragma unroll
  for (int ct = 0; ct < 8; ++ct) {
    const unsigned short* wp = Wb + (size_t)(ct * 16 + c15) * D;
#pragma unroll
    for (int ks = 0; ks < 4; ++ks) {
      s16x8 b = *(const s16x8*)(wp + ks * 32 + grp * 8);
      acc[ct] = __builtin_amdgcn_mfma_f32_16x16x32_bf16(a[ks], b, acc[ct], 0, 0, 0);
    }
  }
#pragma unroll
  for (int ct = 0; ct < 8; ++ct) {
    int col = ct * 16 + c15;
    float bv = bias[col];
#pragma unroll
    for (int r = 0; r < 4; ++r)
      lds[wave][grp * 4 + r][col] = fmaxf(acc[ct][r] + bv, 0.f);
  }
  __syncthreads();
#pragma unroll
  for (int it = 0; it < 4; ++it) {
    int idx = it * 512 + lane * 8;
    int r = idx >> 7, c = idx & 127;
    const float* lp = &lds[wave][r][c];
    f32x4 v0 = *(const f32x4*)lp;
    f32x4 v1 = *(const f32x4*)(lp + 4);
    u16x8 ov;
    ov[0] = f2b_bits(v0[0]); ov[1] = f2b_bits(v0[1]);
    ov[2] = f2b_bits(v0[2]); ov[3] = f2b_bits(v0[3]);
    ov[4] = f2b_bits(v1[0]); ov[5] = f2b_bits(v1[1]);
    ov[6] = f2b_bits(v1[2]); ov[7] = f2b_bits(v1[3]);
    *(u16x8*)(tout + (size_t)(rowbase + r) * D + c) = ov;
  }
}

// ---------------- full layer, block-cooperative (block owns 16 nodes) ----------------
// phase1: each wave gathers 4 nodes (full-row reads) + residual + rmsnorm -> h1 in LDS
// phase2: MLP GEMM column-split across 4 waves; residual+norm -> hout (+ LDS)
// phase3: next-layer edge GEMM column-split -> bf16 t'
template <int WRITE_T>
__global__ __launch_bounds__(256) void k_layer(
    const float* __restrict__ hin,
    const uint32_t* __restrict__ tp,       // bf16x2 rows [NN][64]
    const int* __restrict__ rs, const int* __restrict__ deg, const int* __restrict__ csr,
    const float* __restrict__ gcv, const float* __restrict__ bgcv,
    const unsigned short* __restrict__ Whb, const float* __restrict__ bhv,
    const float* __restrict__ ghv, const float* __restrict__ bghv,
    const unsigned short* __restrict__ Wcb, const float* __restrict__ bcv,
    float* __restrict__ hout, unsigned short* __restrict__ tout) {
  __shared__ float u[16][132];
  int tid = threadIdx.x;
  int wave = tid >> 6, lane = tid & 63;
  int q = lane & 15, g = lane >> 4;
  int rowbase = blockIdx.x * 16;

  // ---- phase 1: gather-max + residual + rmsnorm for 4 nodes per wave ----
  {
    int d0 = lane * 2;
    float2 gc2  = *(const float2*)(gcv + d0);
    float2 bgc2 = *(const float2*)(bgcv + d0);
#pragma unroll
    for (int j = 0; j < 4; ++j) {
      int nl = wave * 4 + j;
      int n = rowbase + nl;
      int r0 = rs[n], r1 = r0 + deg[n];
      float m0 = 0.f, m1 = 0.f;
      int i = r0;
      for (; i + 4 <= r1; i += 4) {
        int s0 = csr[i], s1 = csr[i + 1], s2 = csr[i + 2], s3 = csr[i + 3];
        uint32_t p0 = tp[(size_t)s0 * 64 + lane];
        uint32_t p1 = tp[(size_t)s1 * 64 + lane];
        uint32_t p2 = tp[(size_t)s2 * 64 + lane];
        uint32_t p3 = tp[(size_t)s3 * 64 + lane];
        m0 = fmaxf(fmaxf(m0, blo(p0)), fmaxf(blo(p1), fmaxf(blo(p2), blo(p3))));
        m1 = fmaxf(fmaxf(m1, bhi(p0)), fmaxf(bhi(p1), fmaxf(bhi(p2), bhi(p3))));
      }
      for (; i < r1; ++i) {
        uint32_t p = tp[(size_t)csr[i] * 64 + lane];
        m0 = fmaxf(m0, blo(p));
        m1 = fmaxf(m1, bhi(p));
      }
      float2 hv = *(const float2*)(hin + (size_t)n * D + d0);
      float u0 = hv.x + m0, u1 = hv.y + m1;
      float ss = u0 * u0 + u1 * u1;
#pragma unroll
      for (int off = 32; off; off >>= 1) ss += __shfl_xor(ss, off);
      float rf = rsqrtf(ss * (1.f / D) + EPSV);
      u[nl][d0]     = u0 * rf * gc2.x + bgc2.x;
      u[nl][d0 + 1] = u1 * rf * gc2.y + bgc2.y;
    }
  }
  __syncthreads();

  // ---- phase 2: MLP GEMM, columns split across waves (2 ct-tiles each) ----
  s16x8 a[4];
#pragma unroll
  for (int ks = 0; ks < 4; ++ks) {
    int k0 = ks * 32 + g * 8;
    f32x4 x0 = *(const f32x4*)&u[q][k0];
    f32x4 x1 = *(const f32x4*)&u[q][k0 + 4];
    u16x8 av;
    av[0] = f2b_bits(x0[0]); av[1] = f2b_bits(x0[1]);
    av[2] = f2b_bits(x0[2]); av[3] = f2b_bits(x0[3]);
    av[4] = f2b_bits(x1[0]); av[5] = f2b_bits(x1[1]);
    av[6] = f2b_bits(x1[2]); av[7] = f2b_bits(x1[3]);
    a[ks] = __builtin_bit_cast(s16x8, av);
  }
  f32x4 acc[2];
#pragma unroll
  for (int c2 = 0; c2 < 2; ++c2) { f32x4 z = {0.f, 0.f, 0.f, 0.f}; acc[c2] = z; }
#pragma unroll
  for (int c2 = 0; c2 < 2; ++c2) {
    int ct = wave * 2 + c2;
    const unsigned short* wp = Whb + (size_t)(ct * 16 + q) * D;
#pragma unroll
    for (int ks = 0; ks < 4; ++ks) {
      s16x8 b = *(const s16x8*)(wp + ks * 32 + g * 8);
      acc[c2] = __builtin_amdgcn_mfma_f32_16x16x32_bf16(a[ks], b, acc[c2], 0, 0, 0);
    }
  }
  __syncthreads();
  // residual: u += relu(acc + bias) on this wave's column range
#pragma unroll
  for (int c2 = 0; c2 < 2; ++c2) {
    int col = (wave * 2 + c2) * 16 + q;
    float bv = bhv[col];
#pragma unroll
    for (int r = 0; r < 4; ++r)
      u[g * 4 + r][col] += fmaxf(acc[c2][r] + bv, 0.f);
  }
  __syncthreads();
  // rmsnorm: wave handles rows wave*4..wave*4+3; write h2 to global + LDS
  {
    int d0 = lane * 2;
    float2 gh2  = *(const float2*)(ghv + d0);
    float2 bgh2 = *(const float2*)(bghv + d0);
#pragma unroll
    for (int j = 0; j < 4; ++j) {
      int r = wave * 4 + j;
      float u0 = u[r][d0], u1 = u[r][d0 + 1];
      float ss = u0 * u0 + u1 * u1;
#pragma unroll
      for (int off = 32; off; off >>= 1) ss += __shfl_xor(ss, off);
      float rf = rsqrtf(ss * (1.f / D) + EPSV);
      float o0 = u0 * rf * gh2.x + bgh2.x;
      float o1 = u1 * rf * gh2.y + bgh2.y;
      u[r][d0]     = o0;
      u[r][d0 + 1] = o1;
      float2 o; o.x = o0; o.y = o1;
      *(float2*)(hout + (size_t)(rowbase + r) * D + d0) = o;
    }
  }

  if (WRITE_T) {
    __syncthreads();
    // phase 3: next-layer edge GEMM from LDS h2, column-split
    s16x8 a2[4];
#pragma unroll
    for (int ks = 0; ks < 4; ++ks) {
      int k0 = ks * 32 + g * 8;
      f32x4 x0 = *(const f32x4*)&u[q][k0];
      f32x4 x1 = *(const f32x4*)&u[q][k0 + 4];
      u16x8 av;
      av[0] = f2b_bits(x0[0]); av[1] = f2b_bits(x0[1]);
      av[2] = f2b_bits(x0[2]); av[3] = f2b_bits(x0[3]);
      av[4] = f2b_bits(x1[0]); av[5] = f2b_bits(x1[1]);
      av[6] = f2b_bits(x1[2]); av[7] = f2b_bits(x1[3]);
      a2[ks] = __builtin_bit_cast(s16x8, av);
    }
    f32x4 acc2[2];
#pragma unroll
    for (int c2 = 0; c2 < 2; ++c2) { f32x4 z = {0.f, 0.f, 0.f, 0.f}; acc2[c2] = z; }
#pragma unroll
    for (int c2 = 0; c2 < 2; ++c2) {
      int ct = wave * 2 + c2;
      const unsigned short* wp = Wcb + (size_t)(ct * 16 + q) * D;
#pragma unroll
      for (int ks = 0; ks < 4; ++ks) {
        s16x8 b = *(const s16x8*)(wp + ks * 32 + g * 8);
        acc2[c2] = __builtin_amdgcn_mfma_f32_16x16x32_bf16(a2[ks], b, acc2[c2], 0, 0, 0);
      }
    }
    __syncthreads();
#pragma unroll
    for (int c2 = 0; c2 < 2; ++c2) {
      int col = (wave * 2 + c2) * 16 + q;
      float bv = bcv[col];
#pragma unroll
      for (int r = 0; r < 4; ++r)
        u[g * 4 + r][col] = fmaxf(acc2[c2][r] + bv, 0.f);
    }
    __syncthreads();
    // coalesced bf16 store: thread tid -> row tid>>4, cols (tid&15)*8..+7
    {
      int r = tid >> 4, c = (tid & 15) * 8;
      f32x4 v0 = *(const f32x4*)&u[r][c];
      f32x4 v1 = *(const f32x4*)&u[r][c + 4];
      u16x8 ov;
      ov[0] = f2b_bits(v0[0]); ov[1] = f2b_bits(v0[1]);
      ov[2] = f2b_bits(v0[2]); ov[3] = f2b_bits(v0[3]);
      ov[4] = f2b_bits(v1[0]); ov[5] = f2b_bits(v1[1]);
      ov[6] = f2b_bits(v1[2]); ov[7] = f2b_bits(v1[3]);
      *(u16x8*)(tout + (size_t)(rowbase + r) * D + c) = ov;
    }
  }
}

// ---------------- launch ----------------
extern "C" void kernel_launch(void* const* d_in, const int* in_sizes, int n_in,
                              void* d_out, int out_size, void* d_ws, size_t ws_size,
                              hipStream_t stream) {
  (void)in_sizes; (void)n_in; (void)out_size; (void)ws_size;
  const float* x   = (const float*)d_in[0];
  const int*   e   = (const int*)d_in[1];
  const float* Wc  = (const float*)d_in[2];
  const float* bc  = (const float*)d_in[3];
  const float* gc  = (const float*)d_in[4];
  const float* bgc = (const float*)d_in[5];
  const float* Wh  = (const float*)d_in[6];
  const float* bh  = (const float*)d_in[7];
  const float* gh  = (const float*)d_in[8];
  const float* bgh = (const float*)d_in[9];
  float* out = (float*)d_out;

  char* base = (char*)d_ws;
  unsigned short* t0  = (unsigned short*)(base + 0);          // 10,240,000
  unsigned short* t1  = (unsigned short*)(base + 10240000);   // 10,240,000
  float*          hA  = (float*)(base + 20480000);            // 20,480,000
  unsigned short* wcb = (unsigned short*)(base + 40960000);   //    131,072
  unsigned short* whb = (unsigned short*)(base + 41091072);   //    131,072
  int*            deg = (int*)(base + 41222144);              //    160,000
  int*            cur = (int*)(base + 41382144);              //    160,000
  int*            tot = (int*)(base + 41542144);              //         64
  int*            rs  = (int*)(base + 41542208);              //    160,000
  int*            csr = (int*)(base + 41702208);              //  2,560,000

  k_prep<<<512, 256, 0, stream>>>(Wc, Wh, wcb, whb);
  hipMemsetAsync(deg, 0, 2 * 160000 + 64, stream);   // deg | cur | tot
  k_count<<<2500, 256, 0, stream>>>(e, deg);
  k_alloc<<<157, 256, 0, stream>>>(deg, tot, rs);
  k_fill<<<2500, 256, 0, stream>>>(e, rs, cur, csr);

  // layer-0 t on x
  k_gemm0<<<625, 256, 0, stream>>>(x, wcb, bc, t0);

  unsigned short* tbuf[2] = {t0, t1};
  for (int l = 0; l < NL; ++l) {
    const float* hin = (l == 0) ? x : hA;
    const uint32_t* tin = (const uint32_t*)tbuf[l & 1];
    if (l < NL - 1) {
      k_layer<1><<<2500, 256, 0, stream>>>(
          hin, tin, rs, deg, csr,
          gc + l * D, bgc + l * D,
          whb + (size_t)l * D * D, bh + l * D, gh + l * D, bgh + l * D,
          wcb + (size_t)(l + 1) * D * D, bc + (l + 1) * D,
          hA, tbuf[(l + 1) & 1]);
    } else {
      k_layer<0><<<2500, 256, 0, stream>>>(
          hin, tin, rs, deg, csr,
          gc + l * D, bgc + l * D,
          whb + (size_t)l * D * D, bh + l * D, gh + l * D, bgh + l * D,
          nullptr, nullptr,
          out, nullptr);
    }
  }
}

// Round 5
// 263.102 us; speedup vs baseline: 1.4451x; 1.2620x over previous
//
#include <hip/hip_runtime.h>
#include <hip/hip_bf16.h>
#include <stdint.h>
#include <string.h>

#define NN 40000
#define NE 640000
#define D  128
#define NL 4
#define EPSV 1e-6f

typedef __attribute__((ext_vector_type(8))) short          s16x8;
typedef __attribute__((ext_vector_type(8))) unsigned short u16x8;
typedef __attribute__((ext_vector_type(4))) unsigned short u16x4;
typedef __attribute__((ext_vector_type(4))) float          f32x4;

static __device__ __forceinline__ unsigned short f2b_bits(float f) {
  uint32_t u = __float_as_uint(f);
  uint32_t r = (u + 0x7fffu + ((u >> 16) & 1u)) >> 16;   // RNE
  return (unsigned short)r;
}
static __device__ __forceinline__ float blo(uint32_t p) { return __uint_as_float(p << 16); }
static __device__ __forceinline__ float bhi(uint32_t p) { return __uint_as_float(p & 0xffff0000u); }

// ---------------- weight prep: fp32 -> bf16 bits ----------------
__global__ void k_prep(const float* __restrict__ Wc, const float* __restrict__ Wh,
                       unsigned short* __restrict__ wcb, unsigned short* __restrict__ whb) {
  int i = blockIdx.x * 256 + threadIdx.x;
  if (i < NL * D * D) {
    wcb[i] = f2b_bits(Wc[i]);
    whb[i] = f2b_bits(Wh[i]);
  }
}

// ---------------- CSR build (scan-free) ----------------
__global__ void k_count(const int* __restrict__ e, int* __restrict__ deg) {
  int i = blockIdx.x * 256 + threadIdx.x;
  if (i < NE) atomicAdd(&deg[e[2 * i + 1]], 1);
}

__global__ void k_alloc(const int* __restrict__ deg, int* __restrict__ total,
                        int* __restrict__ rs) {
  int i = blockIdx.x * 256 + threadIdx.x;
  if (i < NN) rs[i] = atomicAdd(total, deg[i]);
}

__global__ void k_fill(const int* __restrict__ e, const int* __restrict__ rs,
                       int* __restrict__ cursor, int* __restrict__ csr) {
  int i = blockIdx.x * 256 + threadIdx.x;
  if (i < NE) {
    int s = e[2 * i + 0];
    int d = e[2 * i + 1];
    int p = atomicAdd(&cursor[d], 1);
    csr[rs[d] + p] = s;
  }
}

// ---------------- layer-0 edge GEMM: t = relu(x @ Wc^T + bc) -> bf16 ----------------
__global__ __launch_bounds__(256) void k_gemm0(
    const float* __restrict__ hin,
    const unsigned short* __restrict__ Wb,
    const float* __restrict__ bias,
    unsigned short* __restrict__ tout) {
  __shared__ float lds[4][16][D];
  int wave = threadIdx.x >> 6, lane = threadIdx.x & 63;
  int rowbase = (blockIdx.x * 4 + wave) * 16;
  int c15 = lane & 15, grp = lane >> 4;

  s16x8 a[4];
  {
    const float* hp = hin + (size_t)(rowbase + c15) * D;
#pragma unroll
    for (int ks = 0; ks < 4; ++ks) {
      int k0 = ks * 32 + grp * 8;
      f32x4 x0 = *(const f32x4*)(hp + k0);
      f32x4 x1 = *(const f32x4*)(hp + k0 + 4);
      u16x8 av;
      av[0] = f2b_bits(x0[0]); av[1] = f2b_bits(x0[1]);
      av[2] = f2b_bits(x0[2]); av[3] = f2b_bits(x0[3]);
      av[4] = f2b_bits(x1[0]); av[5] = f2b_bits(x1[1]);
      av[6] = f2b_bits(x1[2]); av[7] = f2b_bits(x1[3]);
      a[ks] = __builtin_bit_cast(s16x8, av);
    }
  }

  f32x4 acc[8];
#pragma unroll
  for (int ct = 0; ct < 8; ++ct) { f32x4 z = {0.f, 0.f, 0.f, 0.f}; acc[ct] = z; }
#pragma unroll
  for (int ct = 0; ct < 8; ++ct) {
    const unsigned short* wp = Wb + (size_t)(ct * 16 + c15) * D;
#pragma unroll
    for (int ks = 0; ks < 4; ++ks) {
      s16x8 b = *(const s16x8*)(wp + ks * 32 + grp * 8);
      acc[ct] = __builtin_amdgcn_mfma_f32_16x16x32_bf16(a[ks], b, acc[ct], 0, 0, 0);
    }
  }
#pragma unroll
  for (int ct = 0; ct < 8; ++ct) {
    int col = ct * 16 + c15;
    float bv = bias[col];
#pragma unroll
    for (int r = 0; r < 4; ++r)
      lds[wave][grp * 4 + r][col] = fmaxf(acc[ct][r] + bv, 0.f);
  }
  __syncthreads();
#pragma unroll
  for (int it = 0; it < 4; ++it) {
    int idx = it * 512 + lane * 8;
    int r = idx >> 7, c = idx & 127;
    const float* lp = &lds[wave][r][c];
    f32x4 v0 = *(const f32x4*)lp;
    f32x4 v1 = *(const f32x4*)(lp + 4);
    u16x8 ov;
    ov[0] = f2b_bits(v0[0]); ov[1] = f2b_bits(v0[1]);
    ov[2] = f2b_bits(v0[2]); ov[3] = f2b_bits(v0[3]);
    ov[4] = f2b_bits(v1[0]); ov[5] = f2b_bits(v1[1]);
    ov[6] = f2b_bits(v1[2]); ov[7] = f2b_bits(v1[3]);
    *(u16x8*)(tout + (size_t)(rowbase + r) * D + c) = ov;
  }
}

// ---------------- full layer, block-cooperative (block = 8 waves, 16 nodes) ----------
// phase1: half-wave gather — wave w: lanes<32 node 2w, lanes>=32 node 2w+1;
//         one coalesced csr load per node + shfl broadcast; uint2 row granules.
// phase2: MLP GEMM, 1 ct-tile per wave; residual+rmsnorm -> hout (+ LDS)
// phase3: next-layer edge GEMM, 1 ct-tile per wave -> bf16 t'
template <int WRITE_T>
__global__ __launch_bounds__(512) void k_layer(
    const float* __restrict__ hin,
    const uint32_t* __restrict__ tp,       // bf16x2 rows [NN][64]
    const int* __restrict__ rs, const int* __restrict__ deg, const int* __restrict__ csr,
    const float* __restrict__ gcv, const float* __restrict__ bgcv,
    const unsigned short* __restrict__ Whb, const float* __restrict__ bhv,
    const float* __restrict__ ghv, const float* __restrict__ bghv,
    const unsigned short* __restrict__ Wcb, const float* __restrict__ bcv,
    float* __restrict__ hout, unsigned short* __restrict__ tout) {
  __shared__ float u[16][132];
  int tid = threadIdx.x;
  int wave = tid >> 6, lane = tid & 63;
  int q = lane & 15, g = lane >> 4;
  int l = lane & 31;                       // lane within half-wave
  int rowbase = blockIdx.x * 16;

  // ---- phase 1: gather-max + residual + rmsnorm (2 nodes per wave, in halves) ----
  {
    int nl = wave * 2 + (lane >> 5);       // this half's node (block-local)
    int n = rowbase + nl;
    int r0 = rs[n], dn = deg[n];
    const uint2* tq = (const uint2*)tp;    // 8B granules; row = 32 granules

    float m0 = 0.f, m1 = 0.f, m2 = 0.f, m3 = 0.f;
    // fast path: first min(dn,32) edges — 1 coalesced csr load + shfl broadcast
    int cnt = dn < 32 ? dn : 32;
    int off = (l < cnt) ? l : (cnt > 0 ? cnt - 1 : 0);
    int idx = csr[cnt > 0 ? r0 + off : 0];
    int cother = __shfl_xor(cnt, 32);
    int cmax = cnt > cother ? cnt : cother;
    for (int c = 0; c < cmax; c += 8) {
      uint2 p0, p1, p2, p3, p4, p5, p6, p7;
#define GLOAD(k, pv)                                                        \
      {                                                                     \
        int e = c + k; if (e > cnt - 1) e = cnt - 1;                        \
        int sl = e < 0 ? 0 : e;                                             \
        int s = __shfl(idx, (lane & 32) + sl);                              \
        pv = tq[(size_t)s * 32 + l];                                        \
        if (e < 0) { pv.x = 0u; pv.y = 0u; }                                \
      }
      GLOAD(0, p0) GLOAD(1, p1) GLOAD(2, p2) GLOAD(3, p3)
      GLOAD(4, p4) GLOAD(5, p5) GLOAD(6, p6) GLOAD(7, p7)
#undef GLOAD
#define FM(pv)                                                              \
      m0 = fmaxf(m0, blo(pv.x)); m1 = fmaxf(m1, bhi(pv.x));                 \
      m2 = fmaxf(m2, blo(pv.y)); m3 = fmaxf(m3, bhi(pv.y));
      FM(p0) FM(p1) FM(p2) FM(p3) FM(p4) FM(p5) FM(p6) FM(p7)
#undef FM
    }
    // rare tail (deg > 32): divergence-safe, no cross-lane ops
    for (int i = r0 + 32; i < r0 + dn; ++i) {
      int s = csr[i];
      uint2 p = tq[(size_t)s * 32 + l];
      m0 = fmaxf(m0, blo(p.x)); m1 = fmaxf(m1, bhi(p.x));
      m2 = fmaxf(m2, blo(p.y)); m3 = fmaxf(m3, bhi(p.y));
    }

    int d0 = l * 4;                        // this lane's 4 dims
    f32x4 hv = *(const f32x4*)(hin + (size_t)n * D + d0);
    float u0 = hv[0] + m0, u1 = hv[1] + m1, u2 = hv[2] + m2, u3 = hv[3] + m3;
    float ss = u0 * u0 + u1 * u1 + u2 * u2 + u3 * u3;
#pragma unroll
    for (int off2 = 16; off2; off2 >>= 1) ss += __shfl_xor(ss, off2);
    float rf = rsqrtf(ss * (1.f / D) + EPSV);
    f32x4 gc4  = *(const f32x4*)(gcv + d0);
    f32x4 bgc4 = *(const f32x4*)(bgcv + d0);
    f32x4 o;
    o[0] = u0 * rf * gc4[0] + bgc4[0];
    o[1] = u1 * rf * gc4[1] + bgc4[1];
    o[2] = u2 * rf * gc4[2] + bgc4[2];
    o[3] = u3 * rf * gc4[3] + bgc4[3];
    *(f32x4*)&u[nl][d0] = o;
  }
  __syncthreads();

  // ---- phase 2: MLP GEMM, wave handles ct-tile = wave ----
  s16x8 a[4];
#pragma unroll
  for (int ks = 0; ks < 4; ++ks) {
    int k0 = ks * 32 + g * 8;
    f32x4 x0 = *(const f32x4*)&u[q][k0];
    f32x4 x1 = *(const f32x4*)&u[q][k0 + 4];
    u16x8 av;
    av[0] = f2b_bits(x0[0]); av[1] = f2b_bits(x0[1]);
    av[2] = f2b_bits(x0[2]); av[3] = f2b_bits(x0[3]);
    av[4] = f2b_bits(x1[0]); av[5] = f2b_bits(x1[1]);
    av[6] = f2b_bits(x1[2]); av[7] = f2b_bits(x1[3]);
    a[ks] = __builtin_bit_cast(s16x8, av);
  }
  f32x4 acc = {0.f, 0.f, 0.f, 0.f};
  {
    const unsigned short* wp = Whb + (size_t)(wave * 16 + q) * D;
#pragma unroll
    for (int ks = 0; ks < 4; ++ks) {
      s16x8 b = *(const s16x8*)(wp + ks * 32 + g * 8);
      acc = __builtin_amdgcn_mfma_f32_16x16x32_bf16(a[ks], b, acc, 0, 0, 0);
    }
  }
  __syncthreads();                         // all A-frag reads done
  {
    int col = wave * 16 + q;
    float bv = bhv[col];
#pragma unroll
    for (int r = 0; r < 4; ++r)
      u[g * 4 + r][col] += fmaxf(acc[r] + bv, 0.f);
  }
  __syncthreads();
  // rmsnorm: wave handles rows {2*wave, 2*wave+1}; write h2 to global + LDS
  {
    int d0 = lane * 2;
    float2 gh2  = *(const float2*)(ghv + d0);
    float2 bgh2 = *(const float2*)(bghv + d0);
#pragma unroll
    for (int j = 0; j < 2; ++j) {
      int r = wave * 2 + j;
      float u0 = u[r][d0], u1 = u[r][d0 + 1];
      float ss = u0 * u0 + u1 * u1;
#pragma unroll
      for (int off2 = 32; off2; off2 >>= 1) ss += __shfl_xor(ss, off2);
      float rf = rsqrtf(ss * (1.f / D) + EPSV);
      float o0 = u0 * rf * gh2.x + bgh2.x;
      float o1 = u1 * rf * gh2.y + bgh2.y;
      u[r][d0]     = o0;
      u[r][d0 + 1] = o1;
      float2 o; o.x = o0; o.y = o1;
      *(float2*)(hout + (size_t)(rowbase + r) * D + d0) = o;
    }
  }

  if (WRITE_T) {
    __syncthreads();
    // phase 3: next-layer edge GEMM from LDS h2
    s16x8 a2[4];
#pragma unroll
    for (int ks = 0; ks < 4; ++ks) {
      int k0 = ks * 32 + g * 8;
      f32x4 x0 = *(const f32x4*)&u[q][k0];
      f32x4 x1 = *(const f32x4*)&u[q][k0 + 4];
      u16x8 av;
      av[0] = f2b_bits(x0[0]); av[1] = f2b_bits(x0[1]);
      av[2] = f2b_bits(x0[2]); av[3] = f2b_bits(x0[3]);
      av[4] = f2b_bits(x1[0]); av[5] = f2b_bits(x1[1]);
      av[6] = f2b_bits(x1[2]); av[7] = f2b_bits(x1[3]);
      a2[ks] = __builtin_bit_cast(s16x8, av);
    }
    f32x4 acc2 = {0.f, 0.f, 0.f, 0.f};
    {
      const unsigned short* wp = Wcb + (size_t)(wave * 16 + q) * D;
#pragma unroll
      for (int ks = 0; ks < 4; ++ks) {
        s16x8 b = *(const s16x8*)(wp + ks * 32 + g * 8);
        acc2 = __builtin_amdgcn_mfma_f32_16x16x32_bf16(a2[ks], b, acc2, 0, 0, 0);
      }
    }
    __syncthreads();
    {
      int col = wave * 16 + q;
      float bv = bcv[col];
#pragma unroll
      for (int r = 0; r < 4; ++r)
        u[g * 4 + r][col] = fmaxf(acc2[r] + bv, 0.f);
    }
    __syncthreads();
    // coalesced bf16 store: thread -> row tid>>5, cols (tid&31)*4..+3
    {
      int r = tid >> 5, c = (tid & 31) * 4;
      f32x4 v = *(const f32x4*)&u[r][c];
      u16x4 ov;
      ov[0] = f2b_bits(v[0]); ov[1] = f2b_bits(v[1]);
      ov[2] = f2b_bits(v[2]); ov[3] = f2b_bits(v[3]);
      *(u16x4*)(tout + (size_t)(rowbase + r) * D + c) = ov;
    }
  }
}

// ---------------- launch ----------------
extern "C" void kernel_launch(void* const* d_in, const int* in_sizes, int n_in,
                              void* d_out, int out_size, void* d_ws, size_t ws_size,
                              hipStream_t stream) {
  (void)in_sizes; (void)n_in; (void)out_size; (void)ws_size;
  const float* x   = (const float*)d_in[0];
  const int*   e   = (const int*)d_in[1];
  const float* Wc  = (const float*)d_in[2];
  const float* bc  = (const float*)d_in[3];
  const float* gc  = (const float*)d_in[4];
  const float* bgc = (const float*)d_in[5];
  const float* Wh  = (const float*)d_in[6];
  const float* bh  = (const float*)d_in[7];
  const float* gh  = (const float*)d_in[8];
  const float* bgh = (const float*)d_in[9];
  float* out = (float*)d_out;

  char* base = (char*)d_ws;
  unsigned short* t0  = (unsigned short*)(base + 0);          // 10,240,000
  unsigned short* t1  = (unsigned short*)(base + 10240000);   // 10,240,000
  float*          hA  = (float*)(base + 20480000);            // 20,480,000
  unsigned short* wcb = (unsigned short*)(base + 40960000);   //    131,072
  unsigned short* whb = (unsigned short*)(base + 41091072);   //    131,072
  int*            deg = (int*)(base + 41222144);              //    160,000
  int*            cur = (int*)(base + 41382144);              //    160,000
  int*            tot = (int*)(base + 41542144);              //         64
  int*            rs  = (int*)(base + 41542208);              //    160,000
  int*            csr = (int*)(base + 41702208);              //  2,560,000

  k_prep<<<512, 256, 0, stream>>>(Wc, Wh, wcb, whb);
  hipMemsetAsync(deg, 0, 2 * 160000 + 64, stream);   // deg | cur | tot
  k_count<<<2500, 256, 0, stream>>>(e, deg);
  k_alloc<<<157, 256, 0, stream>>>(deg, tot, rs);
  k_fill<<<2500, 256, 0, stream>>>(e, rs, cur, csr);

  // layer-0 t on x
  k_gemm0<<<625, 256, 0, stream>>>(x, wcb, bc, t0);

  unsigned short* tbuf[2] = {t0, t1};
  for (int l = 0; l < NL; ++l) {
    const float* hin = (l == 0) ? x : hA;
    const uint32_t* tin = (const uint32_t*)tbuf[l & 1];
    if (l < NL - 1) {
      k_layer<1><<<2500, 512, 0, stream>>>(
          hin, tin, rs, deg, csr,
          gc + l * D, bgc + l * D,
          whb + (size_t)l * D * D, bh + l * D, gh + l * D, bgh + l * D,
          wcb + (size_t)(l + 1) * D * D, bc + (l + 1) * D,
          hA, tbuf[(l + 1) & 1]);
    } else {
      k_layer<0><<<2500, 512, 0, stream>>>(
          hin, tin, rs, deg, csr,
          gc + l * D, bgc + l * D,
          whb + (size_t)l * D * D, bh + l * D, gh + l * D, bgh + l * D,
          nullptr, nullptr,
          out, nullptr);
    }
  }
}

// Round 6
// 259.171 us; speedup vs baseline: 1.4671x; 1.0152x over previous
//
#include <hip/hip_runtime.h>
#include <hip/hip_bf16.h>
#include <stdint.h>
#include <string.h>

#define NN 40000
#define NE 640000
#define D  128
#define NL 4
#define EPSV 1e-6f

typedef __attribute__((ext_vector_type(8))) short          s16x8;
typedef __attribute__((ext_vector_type(8))) unsigned short u16x8;
typedef __attribute__((ext_vector_type(4))) unsigned short u16x4;
typedef __attribute__((ext_vector_type(4))) float          f32x4;

static __device__ __forceinline__ unsigned short f2b_bits(float f) {
  uint32_t u = __float_as_uint(f);
  uint32_t r = (u + 0x7fffu + ((u >> 16) & 1u)) >> 16;   // RNE
  return (unsigned short)r;
}
static __device__ __forceinline__ float b2f(unsigned short b) {
  return __uint_as_float((uint32_t)b << 16);
}

// ---------------- weight prep: fp32 -> bf16 bits ----------------
__global__ void k_prep(const float* __restrict__ Wc, const float* __restrict__ Wh,
                       unsigned short* __restrict__ wcb, unsigned short* __restrict__ whb) {
  int i = blockIdx.x * 256 + threadIdx.x;
  if (i < NL * D * D) {
    wcb[i] = f2b_bits(Wc[i]);
    whb[i] = f2b_bits(Wh[i]);
  }
}

// ---------------- CSR build (scan-free) ----------------
__global__ void k_count(const int* __restrict__ e, int* __restrict__ deg) {
  int i = blockIdx.x * 256 + threadIdx.x;
  if (i < NE) atomicAdd(&deg[e[2 * i + 1]], 1);
}

__global__ void k_alloc(const int* __restrict__ deg, int* __restrict__ total,
                        int* __restrict__ rs) {
  int i = blockIdx.x * 256 + threadIdx.x;
  if (i < NN) rs[i] = atomicAdd(total, deg[i]);
}

__global__ void k_fill(const int* __restrict__ e, const int* __restrict__ rs,
                       int* __restrict__ cursor, int* __restrict__ csr) {
  int i = blockIdx.x * 256 + threadIdx.x;
  if (i < NE) {
    int s = e[2 * i + 0];
    int d = e[2 * i + 1];
    int p = atomicAdd(&cursor[d], 1);
    csr[rs[d] + p] = s;
  }
}

// ---------------- layer-0 edge GEMM: t = relu(x @ Wc^T + bc) -> bf16 ----------------
__global__ __launch_bounds__(256) void k_gemm0(
    const float* __restrict__ hin,
    const unsigned short* __restrict__ Wb,
    const float* __restrict__ bias,
    unsigned short* __restrict__ tout) {
  __shared__ float lds[4][16][D];
  int wave = threadIdx.x >> 6, lane = threadIdx.x & 63;
  int rowbase = (blockIdx.x * 4 + wave) * 16;
  int c15 = lane & 15, grp = lane >> 4;

  s16x8 a[4];
  {
    const float* hp = hin + (size_t)(rowbase + c15) * D;
#pragma unroll
    for (int ks = 0; ks < 4; ++ks) {
      int k0 = ks * 32 + grp * 8;
      f32x4 x0 = *(const f32x4*)(hp + k0);
      f32x4 x1 = *(const f32x4*)(hp + k0 + 4);
      u16x8 av;
      av[0] = f2b_bits(x0[0]); av[1] = f2b_bits(x0[1]);
      av[2] = f2b_bits(x0[2]); av[3] = f2b_bits(x0[3]);
      av[4] = f2b_bits(x1[0]); av[5] = f2b_bits(x1[1]);
      av[6] = f2b_bits(x1[2]); av[7] = f2b_bits(x1[3]);
      a[ks] = __builtin_bit_cast(s16x8, av);
    }
  }

  f32x4 acc[8];
#pragma unroll
  for (int ct = 0; ct < 8; ++ct) { f32x4 z = {0.f, 0.f, 0.f, 0.f}; acc[ct] = z; }
#pragma unroll
  for (int ct = 0; ct < 8; ++ct) {
    const unsigned short* wp = Wb + (size_t)(ct * 16 + c15) * D;
#pragma unroll
    for (int ks = 0; ks < 4; ++ks) {
      s16x8 b = *(const s16x8*)(wp + ks * 32 + grp * 8);
      acc[ct] = __builtin_amdgcn_mfma_f32_16x16x32_bf16(a[ks], b, acc[ct], 0, 0, 0);
    }
  }
#pragma unroll
  for (int ct = 0; ct < 8; ++ct) {
    int col = ct * 16 + c15;
    float bv = bias[col];
#pragma unroll
    for (int r = 0; r < 4; ++r)
      lds[wave][grp * 4 + r][col] = fmaxf(acc[ct][r] + bv, 0.f);
  }
  __syncthreads();
#pragma unroll
  for (int it = 0; it < 4; ++it) {
    int idx = it * 512 + lane * 8;
    int r = idx >> 7, c = idx & 127;
    const float* lp = &lds[wave][r][c];
    f32x4 v0 = *(const f32x4*)lp;
    f32x4 v1 = *(const f32x4*)(lp + 4);
    u16x8 ov;
    ov[0] = f2b_bits(v0[0]); ov[1] = f2b_bits(v0[1]);
    ov[2] = f2b_bits(v0[2]); ov[3] = f2b_bits(v0[3]);
    ov[4] = f2b_bits(v1[0]); ov[5] = f2b_bits(v1[1]);
    ov[6] = f2b_bits(v1[2]); ov[7] = f2b_bits(v1[3]);
    *(u16x8*)(tout + (size_t)(rowbase + r) * D + c) = ov;
  }
}

// ---------------- full layer, block-cooperative (block = 8 waves, 16 nodes) ----------
// phase1: half-wave gather, integer packed-max (t>=0 => bit order == float order),
//         32-bit byte offsets off uniform base (saddr+voffset addressing).
// phase2: MLP GEMM, 1 ct-tile per wave; residual+rmsnorm -> hout (+ LDS)
// phase3: next-layer edge GEMM, 1 ct-tile per wave -> bf16 t'
template <int WRITE_T>
__global__ __launch_bounds__(512) void k_layer(
    const float* __restrict__ hin,
    const uint32_t* __restrict__ tp,       // bf16x2 rows [NN][64] (256 B rows)
    const int* __restrict__ rs, const int* __restrict__ deg, const int* __restrict__ csr,
    const float* __restrict__ gcv, const float* __restrict__ bgcv,
    const unsigned short* __restrict__ Whb, const float* __restrict__ bhv,
    const float* __restrict__ ghv, const float* __restrict__ bghv,
    const unsigned short* __restrict__ Wcb, const float* __restrict__ bcv,
    float* __restrict__ hout, unsigned short* __restrict__ tout) {
  __shared__ float u[16][132];
  int tid = threadIdx.x;
  int wave = tid >> 6, lane = tid & 63;
  int q = lane & 15, g = lane >> 4;
  int l = lane & 31;                       // lane within half-wave
  int hbase = lane & 32;                   // shuffle base for this half
  int rowbase = blockIdx.x * 16;

  // ---- phase 1: gather-max + residual + rmsnorm (2 nodes per wave, in halves) ----
  {
    int nl = wave * 2 + (lane >> 5);
    int n = rowbase + nl;
    int r0 = rs[n], dn = deg[n];
    const char* tb = (const char*)tp;
    uint32_t loff = (uint32_t)l * 8u;
    int d0 = l * 4;

    // independent loads issued early
    f32x4 hv   = *(const f32x4*)(hin + (size_t)n * D + d0);
    f32x4 gc4  = *(const f32x4*)(gcv + d0);
    f32x4 bgc4 = *(const f32x4*)(bgcv + d0);

    u16x4 ma = {0, 0, 0, 0}, mb = {0, 0, 0, 0};
    // fast path: first min(dn,32) edges — 1 coalesced csr load + shfl broadcast
    int cnt = dn < 32 ? dn : 32;
    int off = (l < cnt) ? l : (cnt - 1);
    int idx = csr[cnt > 0 ? r0 + off : 0];
    int cother = __shfl_xor(cnt, 32);
    int cmax = cnt > cother ? cnt : cother;
    for (int c = 0; c < cmax; c += 8) {
      uint2 p0, p1, p2, p3, p4, p5, p6, p7;
#define GLOAD(k, pv)                                                        \
      {                                                                     \
        int e = c + k; if (e > cnt - 1) e = cnt - 1;                        \
        int sl = e < 0 ? 0 : e;                                             \
        uint32_t s = (uint32_t)__shfl(idx, hbase + sl);                     \
        pv = *(const uint2*)(tb + ((s << 8) + loff));                       \
        if (e < 0) { pv.x = 0u; pv.y = 0u; }                                \
      }
      GLOAD(0, p0) GLOAD(1, p1) GLOAD(2, p2) GLOAD(3, p3)
      GLOAD(4, p4) GLOAD(5, p5) GLOAD(6, p6) GLOAD(7, p7)
#undef GLOAD
      ma = __builtin_elementwise_max(ma, __builtin_bit_cast(u16x4, p0));
      mb = __builtin_elementwise_max(mb, __builtin_bit_cast(u16x4, p1));
      ma = __builtin_elementwise_max(ma, __builtin_bit_cast(u16x4, p2));
      mb = __builtin_elementwise_max(mb, __builtin_bit_cast(u16x4, p3));
      ma = __builtin_elementwise_max(ma, __builtin_bit_cast(u16x4, p4));
      mb = __builtin_elementwise_max(mb, __builtin_bit_cast(u16x4, p5));
      ma = __builtin_elementwise_max(ma, __builtin_bit_cast(u16x4, p6));
      mb = __builtin_elementwise_max(mb, __builtin_bit_cast(u16x4, p7));
    }
    // rare tail (deg > 32): divergence-safe, no cross-lane ops
    for (int i = r0 + 32; i < r0 + dn; ++i) {
      uint32_t s = (uint32_t)csr[i];
      uint2 p = *(const uint2*)(tb + ((s << 8) + loff));
      ma = __builtin_elementwise_max(ma, __builtin_bit_cast(u16x4, p));
    }
    ma = __builtin_elementwise_max(ma, mb);

    float u0 = hv[0] + b2f(ma[0]);
    float u1 = hv[1] + b2f(ma[1]);
    float u2 = hv[2] + b2f(ma[2]);
    float u3 = hv[3] + b2f(ma[3]);
    float ss = u0 * u0 + u1 * u1 + u2 * u2 + u3 * u3;
#pragma unroll
    for (int off2 = 16; off2; off2 >>= 1) ss += __shfl_xor(ss, off2);
    float rf = rsqrtf(ss * (1.f / D) + EPSV);
    f32x4 o;
    o[0] = u0 * rf * gc4[0] + bgc4[0];
    o[1] = u1 * rf * gc4[1] + bgc4[1];
    o[2] = u2 * rf * gc4[2] + bgc4[2];
    o[3] = u3 * rf * gc4[3] + bgc4[3];
    *(f32x4*)&u[nl][d0] = o;
  }
  __syncthreads();

  // ---- phase 2: MLP GEMM, wave handles ct-tile = wave ----
  const char* whB = (const char*)Whb;
  uint32_t wrow = (uint32_t)(wave * 16 + q) * (D * 2);
  s16x8 a[4];
#pragma unroll
  for (int ks = 0; ks < 4; ++ks) {
    int k0 = ks * 32 + g * 8;
    f32x4 x0 = *(const f32x4*)&u[q][k0];
    f32x4 x1 = *(const f32x4*)&u[q][k0 + 4];
    u16x8 av;
    av[0] = f2b_bits(x0[0]); av[1] = f2b_bits(x0[1]);
    av[2] = f2b_bits(x0[2]); av[3] = f2b_bits(x0[3]);
    av[4] = f2b_bits(x1[0]); av[5] = f2b_bits(x1[1]);
    av[6] = f2b_bits(x1[2]); av[7] = f2b_bits(x1[3]);
    a[ks] = __builtin_bit_cast(s16x8, av);
  }
  f32x4 acc = {0.f, 0.f, 0.f, 0.f};
#pragma unroll
  for (int ks = 0; ks < 4; ++ks) {
    s16x8 b = *(const s16x8*)(whB + wrow + (uint32_t)(ks * 32 + g * 8) * 2);
    acc = __builtin_amdgcn_mfma_f32_16x16x32_bf16(a[ks], b, acc, 0, 0, 0);
  }
  __syncthreads();                         // all A-frag reads done
  {
    int col = wave * 16 + q;
    float bv = bhv[col];
#pragma unroll
    for (int r = 0; r < 4; ++r)
      u[g * 4 + r][col] += fmaxf(acc[r] + bv, 0.f);
  }
  __syncthreads();
  // rmsnorm: wave handles rows {2*wave, 2*wave+1}; write h2 to global + LDS
  {
    int d0 = lane * 2;
    float2 gh2  = *(const float2*)(ghv + d0);
    float2 bgh2 = *(const float2*)(bghv + d0);
#pragma unroll
    for (int j = 0; j < 2; ++j) {
      int r = wave * 2 + j;
      float u0 = u[r][d0], u1 = u[r][d0 + 1];
      float ss = u0 * u0 + u1 * u1;
#pragma unroll
      for (int off2 = 32; off2; off2 >>= 1) ss += __shfl_xor(ss, off2);
      float rf = rsqrtf(ss * (1.f / D) + EPSV);
      float o0 = u0 * rf * gh2.x + bgh2.x;
      float o1 = u1 * rf * gh2.y + bgh2.y;
      u[r][d0]     = o0;
      u[r][d0 + 1] = o1;
      float2 o; o.x = o0; o.y = o1;
      *(float2*)(hout + (size_t)(rowbase + r) * D + d0) = o;
    }
  }

  if (WRITE_T) {
    __syncthreads();
    // phase 3: next-layer edge GEMM from LDS h2
    const char* wcB = (const char*)Wcb;
    s16x8 a2[4];
#pragma unroll
    for (int ks = 0; ks < 4; ++ks) {
      int k0 = ks * 32 + g * 8;
      f32x4 x0 = *(const f32x4*)&u[q][k0];
      f32x4 x1 = *(const f32x4*)&u[q][k0 + 4];
      u16x8 av;
      av[0] = f2b_bits(x0[0]); av[1] = f2b_bits(x0[1]);
      av[2] = f2b_bits(x0[2]); av[3] = f2b_bits(x0[3]);
      av[4] = f2b_bits(x1[0]); av[5] = f2b_bits(x1[1]);
      av[6] = f2b_bits(x1[2]); av[7] = f2b_bits(x1[3]);
      a2[ks] = __builtin_bit_cast(s16x8, av);
    }
    f32x4 acc2 = {0.f, 0.f, 0.f, 0.f};
#pragma unroll
    for (int ks = 0; ks < 4; ++ks) {
      s16x8 b = *(const s16x8*)(wcB + wrow + (uint32_t)(ks * 32 + g * 8) * 2);
      acc2 = __builtin_amdgcn_mfma_f32_16x16x32_bf16(a2[ks], b, acc2, 0, 0, 0);
    }
    __syncthreads();
    {
      int col = wave * 16 + q;
      float bv = bcv[col];
#pragma unroll
      for (int r = 0; r < 4; ++r)
        u[g * 4 + r][col] = fmaxf(acc2[r] + bv, 0.f);
    }
    __syncthreads();
    // coalesced bf16 store: thread -> row tid>>5, cols (tid&31)*4..+3
    {
      int r = tid >> 5, c = (tid & 31) * 4;
      f32x4 v = *(const f32x4*)&u[r][c];
      u16x4 ov;
      ov[0] = f2b_bits(v[0]); ov[1] = f2b_bits(v[1]);
      ov[2] = f2b_bits(v[2]); ov[3] = f2b_bits(v[3]);
      *(u16x4*)(tout + (size_t)(rowbase + r) * D + c) = ov;
    }
  }
}

// ---------------- launch ----------------
extern "C" void kernel_launch(void* const* d_in, const int* in_sizes, int n_in,
                              void* d_out, int out_size, void* d_ws, size_t ws_size,
                              hipStream_t stream) {
  (void)in_sizes; (void)n_in; (void)out_size; (void)ws_size;
  const float* x   = (const float*)d_in[0];
  const int*   e   = (const int*)d_in[1];
  const float* Wc  = (const float*)d_in[2];
  const float* bc  = (const float*)d_in[3];
  const float* gc  = (const float*)d_in[4];
  const float* bgc = (const float*)d_in[5];
  const float* Wh  = (const float*)d_in[6];
  const float* bh  = (const float*)d_in[7];
  const float* gh  = (const float*)d_in[8];
  const float* bgh = (const float*)d_in[9];
  float* out = (float*)d_out;

  char* base = (char*)d_ws;
  unsigned short* t0  = (unsigned short*)(base + 0);          // 10,240,000
  unsigned short* t1  = (unsigned short*)(base + 10240000);   // 10,240,000
  float*          hA  = (float*)(base + 20480000);            // 20,480,000
  unsigned short* wcb = (unsigned short*)(base + 40960000);   //    131,072
  unsigned short* whb = (unsigned short*)(base + 41091072);   //    131,072
  int*            deg = (int*)(base + 41222144);              //    160,000
  int*            cur = (int*)(base + 41382144);              //    160,000
  int*            tot = (int*)(base + 41542144);              //         64
  int*            rs  = (int*)(base + 41542208);              //    160,000
  int*            csr = (int*)(base + 41702208);              //  2,560,000

  k_prep<<<512, 256, 0, stream>>>(Wc, Wh, wcb, whb);
  hipMemsetAsync(deg, 0, 2 * 160000 + 64, stream);   // deg | cur | tot
  k_count<<<2500, 256, 0, stream>>>(e, deg);
  k_alloc<<<157, 256, 0, stream>>>(deg, tot, rs);
  k_fill<<<2500, 256, 0, stream>>>(e, rs, cur, csr);

  // layer-0 t on x
  k_gemm0<<<625, 256, 0, stream>>>(x, wcb, bc, t0);

  unsigned short* tbuf[2] = {t0, t1};
  for (int l = 0; l < NL; ++l) {
    const float* hin = (l == 0) ? x : hA;
    const uint32_t* tin = (const uint32_t*)tbuf[l & 1];
    if (l < NL - 1) {
      k_layer<1><<<2500, 512, 0, stream>>>(
          hin, tin, rs, deg, csr,
          gc + l * D, bgc + l * D,
          whb + (size_t)l * D * D, bh + l * D, gh + l * D, bgh + l * D,
          wcb + (size_t)(l + 1) * D * D, bc + (l + 1) * D,
          hA, tbuf[(l + 1) & 1]);
    } else {
      k_layer<0><<<2500, 512, 0, stream>>>(
          hin, tin, rs, deg, csr,
          gc + l * D, bgc + l * D,
          whb + (size_t)l * D * D, bh + l * D, gh + l * D, bgh + l * D,
          nullptr, nullptr,
          out, nullptr);
    }
  }
}